// Round 5
// baseline (433.496 us; speedup 1.0000x reference)
//
#include <hip/hip_runtime.h>

typedef unsigned short u16;
typedef __attribute__((ext_vector_type(8))) short bf16x8;
typedef __attribute__((ext_vector_type(4))) float f32x4;

#define MFMA(a, b, c) __builtin_amdgcn_mfma_f32_16x16x32_bf16(a, b, c, 0, 0, 0)
#define EXP2(x) exp2f(x)

// async global->LDS, 16B per lane; lds ptr must be wave-uniform base.
#define ASYNC16(g, l)                                                      \
  __builtin_amdgcn_global_load_lds(                                        \
      (const __attribute__((address_space(1))) void*)(g),                  \
      (__attribute__((address_space(3))) void*)(l), 16, 0, 0)

__device__ __forceinline__ u16 f2bf(float x) {
  union { float f; unsigned u; } v; v.f = x;
  unsigned r = (v.u + 0x7fffu + ((v.u >> 16) & 1u)) >> 16;
  return (u16)r;
}

// pack two f32 -> bf16x2 (round-half-up)
__device__ __forceinline__ unsigned pack_bf2(float a, float b) {
  unsigned ua = __float_as_uint(a) + 0x8000u;
  unsigned ub = __float_as_uint(b) + 0x8000u;
  return __builtin_amdgcn_perm(ub, ua, 0x07060302u);
}

// ---------------- transpose + fp32->bf16 (w_in, w_out) ----------------
__global__ void transpose_to_bf16(const float* __restrict__ in, u16* __restrict__ out,
                                  int R, int C) {
  __shared__ float tile[32][33];
  int c0 = blockIdx.x * 32, r0 = blockIdx.y * 32;
  int tx = threadIdx.x, ty = threadIdx.y;  // 32 x 8
#pragma unroll
  for (int i = 0; i < 32; i += 8)
    tile[ty + i][tx] = in[(size_t)(r0 + ty + i) * C + c0 + tx];
  __syncthreads();
#pragma unroll
  for (int i = 0; i < 32; i += 8)
    out[(size_t)(c0 + ty + i) * R + r0 + tx] = f2bf(tile[tx][ty + i]);
}

// ---------------- fp32 -> bf16 (x) ----------------
__global__ void f32_to_bf16_vec(const float4* __restrict__ in, uint2* __restrict__ out) {
  int idx = blockIdx.x * 256 + threadIdx.x;
  float4 v = in[idx];
  out[idx] = make_uint2(pack_bf2(v.x, v.y), pack_bf2(v.z, v.w));
}

// ---------------- GEMM (m97 structure): C = A * Bt^T + bias ----------------
#define BM 128
#define BN 128
#define BK 64

template <int OUT_F32>
__global__ __launch_bounds__(256, 2) void gemm_bt(const u16* __restrict__ A,
                                                  const u16* __restrict__ Bt,
                                                  const float* __restrict__ bias,
                                                  void* __restrict__ Cout,
                                                  int M, int N, int K, int ldc,
                                                  int sc_lo, int sc_hi, float qs) {
  __shared__ __align__(16) u16 As[BM * BK];
  __shared__ __align__(16) u16 Bs[BN * BK];
  int bn = blockIdx.x * BN, bm = blockIdx.y * BM;
  int tid = threadIdx.x;
  int wave = tid >> 6, lane = tid & 63;
  int quad = lane >> 4, l16 = lane & 15;
  int wm = (wave >> 1) * 64, wn = (wave & 1) * 64;

  f32x4 acc[4][4] = {};

  int lrow = lane >> 3, lcol = (lane & 7) * 8;
  const u16* gA = A + (size_t)(bm + wave * 8 + lrow) * K + lcol;
  const u16* gB = Bt + (size_t)(bn + wave * 8 + lrow) * K + lcol;
  u16* lA = &As[wave * 8 * BK];
  u16* lB = &Bs[wave * 8 * BK];

  for (int k0 = 0; k0 < K; k0 += BK) {
#pragma unroll
    for (int p = 0; p < 4; ++p) {
      ASYNC16(gA + (size_t)p * 32 * K, lA + p * 32 * BK);
      ASYNC16(gB + (size_t)p * 32 * K, lB + p * 32 * BK);
    }
    gA += BK;
    gB += BK;
    __syncthreads();
#pragma unroll
    for (int kk = 0; kk < BK; kk += 32) {
      bf16x8 af[4], bfr[4];
#pragma unroll
      for (int i = 0; i < 4; ++i)
        af[i] = *(const bf16x8*)&As[(wm + 16 * i + l16) * BK + kk + quad * 8];
#pragma unroll
      for (int j = 0; j < 4; ++j)
        bfr[j] = *(const bf16x8*)&Bs[(wn + 16 * j + l16) * BK + kk + quad * 8];
#pragma unroll
      for (int i = 0; i < 4; ++i)
#pragma unroll
        for (int j = 0; j < 4; ++j)
          acc[i][j] = MFMA(af[i], bfr[j], acc[i][j]);
    }
    __syncthreads();
  }

#pragma unroll
  for (int i = 0; i < 4; ++i) {
#pragma unroll
    for (int j = 0; j < 4; ++j) {
      int gn = bn + wn + 16 * j + l16;
      float bv = bias[gn];
      float sc = (gn >= sc_lo && gn < sc_hi) ? qs : 1.0f;
#pragma unroll
      for (int r = 0; r < 4; ++r) {
        int gm = bm + wm + 16 * i + quad * 4 + r;
        float v = (acc[i][j][r] + bv) * sc;
        if (OUT_F32)
          ((float*)Cout)[(size_t)gm * ldc + gn] = v;
        else
          ((u16*)Cout)[(size_t)gm * ldc + gn] = f2bf(v);
      }
    }
  }
}

#define SEQ 2048
#define ROWS3 3072

// ---------------- V transpose: kqv V-chunk -> vt[bh][d][s-perm] ----------------
// Within each 64-key tile, key k is stored at position 4*(k&15)+(k>>4) so the
// attention kernel's packed-P layout lines up with contiguous vf loads.
__global__ void v_transpose(const u16* __restrict__ kqv, u16* __restrict__ vt) {
  int bh = blockIdx.y;
  int b = bh >> 4, h = bh & 15;
  int t0 = blockIdx.x * 64;
  int tid = threadIdx.x;
  __shared__ u16 tile[64][72];  // [k][d]
  int r = tid >> 3, c = (tid & 7) * 8;
#pragma unroll
  for (int p = 0; p < 2; ++p)
    *(uint4*)&tile[p * 32 + r][c] =
        *(const uint4*)&kqv[(size_t)b * SEQ * ROWS3 + (size_t)(t0 + p * 32 + r) * ROWS3 +
                            2048 + h * 64 + c];
  __syncthreads();
#pragma unroll
  for (int p = 0; p < 2; ++p) {
    int d = p * 32 + r;
    u16 tmp[8];
#pragma unroll
    for (int i = 0; i < 8; ++i) {
      int pos = c + i;
      int k = 16 * (pos & 3) + (pos >> 2);  // inverse of perm
      tmp[i] = tile[k][d];
    }
    *(uint4*)&vt[(size_t)bh * 64 * SEQ + (size_t)d * SEQ + t0 + c] = *(uint4*)tmp;
  }
}

// ---------------- flash attention v5 ----------------
// 256 thr = 4 waves x 32 q-rows. K frags direct from global; V frags direct
// from pre-transposed+permuted vt. LDS only for the per-wave P round-trip.
// NO barriers in the loop. Q pre-scaled by 0.125*log2e; ones-MFMA row sum.
#define LDP 68

__global__ __launch_bounds__(256, 4) void attn_kernel(const u16* __restrict__ kqv,
                                                      const u16* __restrict__ vt,
                                                      u16* __restrict__ out) {
  int bh = blockIdx.y;
  int b = bh >> 4, h = bh & 15;
  int tid = threadIdx.x, wave = tid >> 6, lane = tid & 63;
  int quad = lane >> 4, l16 = lane & 15;

  __shared__ __align__(16) u16 Ps[4][32 * LDP];  // per-wave P [32 q][64 perm-key]

  const u16* base = kqv + (size_t)b * SEQ * ROWS3;
  const u16* vbase = vt + (size_t)bh * 64 * SEQ;
  int hcol = h * 64;

  // Q fragments: wave owns 32 q-rows = 2 MFMA row-tiles, resident
  bf16x8 qf[2][2];
#pragma unroll
  for (int t = 0; t < 2; ++t) {
    int s = blockIdx.x * 128 + wave * 32 + t * 16 + l16;
    const u16* qrow = base + (size_t)s * ROWS3 + 1024 + hcol;  // Q_OFF=1024
    qf[t][0] = *(const bf16x8*)(qrow + quad * 8);
    qf[t][1] = *(const bf16x8*)(qrow + 32 + quad * 8);
  }

  bf16x8 ones;
#pragma unroll
  for (int i = 0; i < 8; ++i) ones[i] = (short)0x3F80;

  f32x4 o[2][4] = {};
  f32x4 ol[2] = {};
  u16* pw = &Ps[wave][0];

  for (int t0 = 0; t0 < SEQ; t0 += 64) {
    // K fragments direct from global (B-frag: lane l16 = key, quad*8 = d)
    bf16x8 kf[4][2];
#pragma unroll
    for (int j = 0; j < 4; ++j) {
      const u16* krow = base + (size_t)(t0 + 16 * j + l16) * ROWS3 + hcol;  // K_OFF=0
      kf[j][0] = *(const bf16x8*)(krow + quad * 8);
      kf[j][1] = *(const bf16x8*)(krow + 32 + quad * 8);
    }

    f32x4 s[2][4] = {};
#pragma unroll
    for (int t = 0; t < 2; ++t)
#pragma unroll
      for (int j = 0; j < 4; ++j) {
        s[t][j] = MFMA(qf[t][0], kf[j][0], s[t][j]);
        s[t][j] = MFMA(qf[t][1], kf[j][1], s[t][j]);
      }

    // exp2 + pack: score s[t][j][r] = key 16j+l16 -> perm position 4*l16+j
#pragma unroll
    for (int t = 0; t < 2; ++t)
#pragma unroll
      for (int r = 0; r < 4; ++r) {
        float p0 = EXP2(s[t][0][r]);
        float p1 = EXP2(s[t][1][r]);
        float p2 = EXP2(s[t][2][r]);
        float p3 = EXP2(s[t][3][r]);
        uint2 pk;
        pk.x = pack_bf2(p0, p1);
        pk.y = pack_bf2(p2, p3);
        *(uint2*)&pw[(t * 16 + quad * 4 + r) * LDP + 4 * l16] = pk;
      }

    // V fragments direct from vt (B-frag: lane l16 = d, quad*8 = perm-key)
    bf16x8 vf[4][2];
#pragma unroll
    for (int dt = 0; dt < 4; ++dt) {
      const u16* vrow = vbase + (size_t)(16 * dt + l16) * SEQ + t0;
      vf[dt][0] = *(const bf16x8*)(vrow + quad * 8);
      vf[dt][1] = *(const bf16x8*)(vrow + 32 + quad * 8);
    }

    // PV + row-sum (wave-synchronous Ps read-after-write)
#pragma unroll
    for (int t = 0; t < 2; ++t) {
      bf16x8 pa0 = *(const bf16x8*)&pw[(t * 16 + l16) * LDP + quad * 8];
      bf16x8 pa1 = *(const bf16x8*)&pw[(t * 16 + l16) * LDP + 32 + quad * 8];
#pragma unroll
      for (int d = 0; d < 4; ++d) {
        o[t][d] = MFMA(pa0, vf[d][0], o[t][d]);
        o[t][d] = MFMA(pa1, vf[d][1], o[t][d]);
      }
      ol[t] = MFMA(pa0, ones, ol[t]);
      ol[t] = MFMA(pa1, ones, ol[t]);
    }
  }

  // epilogue: O /= l, merge heads
#pragma unroll
  for (int t = 0; t < 2; ++t)
#pragma unroll
    for (int r = 0; r < 4; ++r) {
      float inv = 1.0f / ol[t][r];
      int s = blockIdx.x * 128 + wave * 32 + t * 16 + quad * 4 + r;
      u16* orow = out + (size_t)(b * SEQ + s) * 1024 + hcol;
#pragma unroll
      for (int d = 0; d < 4; ++d) orow[16 * d + l16] = f2bf(o[t][d][r] * inv);
    }
}

extern "C" void kernel_launch(void* const* d_in, const int* in_sizes, int n_in,
                              void* d_out, int out_size, void* d_ws, size_t ws_size,
                              hipStream_t stream) {
  const float* x     = (const float*)d_in[0];
  const float* w_in  = (const float*)d_in[1];
  const float* b_in  = (const float*)d_in[2];
  const float* w_out = (const float*)d_in[3];
  const float* b_out = (const float*)d_in[4];
  float* outp = (float*)d_out;

  char* p = (char*)d_ws;
  u16* wT_in  = (u16*)p; p += (size_t)3072 * 1024 * 2;
  u16* wT_out = (u16*)p; p += (size_t)1024 * 1024 * 2;
  u16* xb     = (u16*)p; p += (size_t)8192 * 1024 * 2;  // reused as vt after GEMM1
  u16* kqv    = (u16*)p; p += (size_t)8192 * 3072 * 2;
  u16* attn   = (u16*)p;
  u16* vtbuf  = xb;  // xb dead after GEMM1; vt is 64*64*2048 u16 = 16 MB, same size

  transpose_to_bf16<<<dim3(3072 / 32, 1024 / 32), dim3(32, 8), 0, stream>>>(w_in, wT_in, 1024, 3072);
  transpose_to_bf16<<<dim3(1024 / 32, 1024 / 32), dim3(32, 8), 0, stream>>>(w_out, wT_out, 1024, 1024);
  f32_to_bf16_vec<<<dim3(8192), dim3(256), 0, stream>>>((const float4*)x, (uint2*)xb);

  const float QSCALE = 0.125f * 1.44269504088896f;
  gemm_bt<0><<<dim3(3072 / BN, 8192 / BM), 256, 0, stream>>>(
      xb, wT_in, b_in, (void*)kqv, 8192, 3072, 1024, 3072, 1024, 2048, QSCALE);

  v_transpose<<<dim3(SEQ / 64, 64), 256, 0, stream>>>(kqv, vtbuf);

  attn_kernel<<<dim3(SEQ / 128, 64), 256, 0, stream>>>(kqv, vtbuf, attn);

  gemm_bt<1><<<dim3(1024 / BN, 8192 / BM), 256, 0, stream>>>(
      attn, wT_out, b_out, (void*)outp, 8192, 1024, 1024, 1024, 0, 0, 1.0f);
}

// Round 7
// 308.222 us; speedup vs baseline: 1.4064x; 1.4064x over previous
//
#include <hip/hip_runtime.h>

typedef unsigned short u16;
typedef __attribute__((ext_vector_type(8))) short bf16x8;
typedef __attribute__((ext_vector_type(4))) float f32x4;

#define MFMA(a, b, c) __builtin_amdgcn_mfma_f32_16x16x32_bf16(a, b, c, 0, 0, 0)
#define EXP2(x) exp2f(x)

// async global->LDS, 16B per lane; lds ptr must be wave-uniform base.
#define ASYNC16(g, l)                                                      \
  __builtin_amdgcn_global_load_lds(                                        \
      (const __attribute__((address_space(1))) void*)(g),                  \
      (__attribute__((address_space(3))) void*)(l), 16, 0, 0)

__device__ __forceinline__ u16 f2bf(float x) {
  union { float f; unsigned u; } v; v.f = x;
  unsigned r = (v.u + 0x7fffu + ((v.u >> 16) & 1u)) >> 16;
  return (u16)r;
}

// pack two f32 -> bf16x2 (round-half-up)
__device__ __forceinline__ unsigned pack_bf2(float a, float b) {
  unsigned ua = __float_as_uint(a) + 0x8000u;
  unsigned ub = __float_as_uint(b) + 0x8000u;
  return __builtin_amdgcn_perm(ub, ua, 0x07060302u);
}

// ---------------- transpose + fp32->bf16 (w_in, w_out) ----------------
__global__ void transpose_to_bf16(const float* __restrict__ in, u16* __restrict__ out,
                                  int R, int C) {
  __shared__ float tile[32][33];
  int c0 = blockIdx.x * 32, r0 = blockIdx.y * 32;
  int tx = threadIdx.x, ty = threadIdx.y;  // 32 x 8
#pragma unroll
  for (int i = 0; i < 32; i += 8)
    tile[ty + i][tx] = in[(size_t)(r0 + ty + i) * C + c0 + tx];
  __syncthreads();
#pragma unroll
  for (int i = 0; i < 32; i += 8)
    out[(size_t)(c0 + ty + i) * R + r0 + tx] = f2bf(tile[tx][ty + i]);
}

// ---------------- fp32 -> bf16 (x) ----------------
__global__ void f32_to_bf16_vec(const float4* __restrict__ in, uint2* __restrict__ out) {
  int idx = blockIdx.x * 256 + threadIdx.x;
  float4 v = in[idx];
  out[idx] = make_uint2(pack_bf2(v.x, v.y), pack_bf2(v.z, v.w));
}

// ---------------- GEMM (m97 structure): C = A * Bt^T + bias ----------------
#define BM 128
#define BN 128
#define BK 64

template <int OUT_F32>
__global__ __launch_bounds__(256, 2) void gemm_bt(const u16* __restrict__ A,
                                                  const u16* __restrict__ Bt,
                                                  const float* __restrict__ bias,
                                                  void* __restrict__ Cout,
                                                  int M, int N, int K, int ldc,
                                                  int sc_lo, int sc_hi, float qs) {
  __shared__ __align__(16) u16 As[BM * BK];
  __shared__ __align__(16) u16 Bs[BN * BK];
  int bn = blockIdx.x * BN, bm = blockIdx.y * BM;
  int tid = threadIdx.x;
  int wave = tid >> 6, lane = tid & 63;
  int quad = lane >> 4, l16 = lane & 15;
  int wm = (wave >> 1) * 64, wn = (wave & 1) * 64;

  f32x4 acc[4][4] = {};

  int lrow = lane >> 3, lcol = (lane & 7) * 8;
  const u16* gA = A + (size_t)(bm + wave * 8 + lrow) * K + lcol;
  const u16* gB = Bt + (size_t)(bn + wave * 8 + lrow) * K + lcol;
  u16* lA = &As[wave * 8 * BK];
  u16* lB = &Bs[wave * 8 * BK];

  for (int k0 = 0; k0 < K; k0 += BK) {
#pragma unroll
    for (int p = 0; p < 4; ++p) {
      ASYNC16(gA + (size_t)p * 32 * K, lA + p * 32 * BK);
      ASYNC16(gB + (size_t)p * 32 * K, lB + p * 32 * BK);
    }
    gA += BK;
    gB += BK;
    __syncthreads();
#pragma unroll
    for (int kk = 0; kk < BK; kk += 32) {
      bf16x8 af[4], bfr[4];
#pragma unroll
      for (int i = 0; i < 4; ++i)
        af[i] = *(const bf16x8*)&As[(wm + 16 * i + l16) * BK + kk + quad * 8];
#pragma unroll
      for (int j = 0; j < 4; ++j)
        bfr[j] = *(const bf16x8*)&Bs[(wn + 16 * j + l16) * BK + kk + quad * 8];
#pragma unroll
      for (int i = 0; i < 4; ++i)
#pragma unroll
        for (int j = 0; j < 4; ++j)
          acc[i][j] = MFMA(af[i], bfr[j], acc[i][j]);
    }
    __syncthreads();
  }

#pragma unroll
  for (int i = 0; i < 4; ++i) {
#pragma unroll
    for (int j = 0; j < 4; ++j) {
      int gn = bn + wn + 16 * j + l16;
      float bv = bias[gn];
      float sc = (gn >= sc_lo && gn < sc_hi) ? qs : 1.0f;
#pragma unroll
      for (int r = 0; r < 4; ++r) {
        int gm = bm + wm + 16 * i + quad * 4 + r;
        float v = (acc[i][j][r] + bv) * sc;
        if (OUT_F32)
          ((float*)Cout)[(size_t)gm * ldc + gn] = v;
        else
          ((u16*)Cout)[(size_t)gm * ldc + gn] = f2bf(v);
      }
    }
  }
}

#define SEQ 2048
#define ROWS3 3072

// ---------------- V transpose: kqv V-chunk -> vt[bh][d][s-perm] ----------------
// Within each 64-key tile, key k is stored at position 4*(k&15)+(k>>4) so the
// attention kernel's packed-P layout lines up with contiguous vf loads.
__global__ void v_transpose(const u16* __restrict__ kqv, u16* __restrict__ vt) {
  int bh = blockIdx.y;
  int b = bh >> 4, h = bh & 15;
  int t0 = blockIdx.x * 64;
  int tid = threadIdx.x;
  __shared__ u16 tile[64][72];  // [k][d]
  int r = tid >> 3, c = (tid & 7) * 8;
#pragma unroll
  for (int p = 0; p < 2; ++p)
    *(uint4*)&tile[p * 32 + r][c] =
        *(const uint4*)&kqv[(size_t)b * SEQ * ROWS3 + (size_t)(t0 + p * 32 + r) * ROWS3 +
                            2048 + h * 64 + c];
  __syncthreads();
#pragma unroll
  for (int p = 0; p < 2; ++p) {
    int d = p * 32 + r;
    u16 tmp[8];
#pragma unroll
    for (int i = 0; i < 8; ++i) {
      int pos = c + i;
      int k = 16 * (pos & 3) + (pos >> 2);  // inverse of perm
      tmp[i] = tile[k][d];
    }
    *(uint4*)&vt[(size_t)bh * 64 * SEQ + (size_t)d * SEQ + t0 + c] = *(uint4*)tmp;
  }
}

// ---------------- flash attention v7 ----------------
// 256 thr = 4 waves x 32 q-rows. FULLY double-buffered K and Vt staging via
// lane-permuted global_load_lds (interleaved 8-row blocks, conflict-free).
// ONE barrier per iter; prefetch of tile t0+64 into [cur^1] issued right after
// it, so reads ([cur]) and in-flight writes ([cur^1]) never alias.
// Ps is XOR-swizzled (LDP=64): phys = row*64 + (elem ^ ((row&7)*8)).
// Total LDS 40960 B -> exactly 4 blocks/CU. Grid 1024 = 4/CU resident.
// XCD swizzle: g = qtile*64 + bh.
__global__ __launch_bounds__(256, 4) void attn_kernel(const u16* __restrict__ kqv,
                                                      const u16* __restrict__ vt,
                                                      u16* __restrict__ out) {
  int g = blockIdx.x;
  int bh = g & 63, qtile = g >> 6;
  int b = bh >> 4, h = bh & 15;
  int tid = threadIdx.x, wave = tid >> 6, lane = tid & 63;
  int quad = lane >> 4, l16 = lane & 15;

  __shared__ __align__(16) u16 Ks[2][64 * 64];   // dbuf, interleaved 8-row blocks
  __shared__ __align__(16) u16 Vts[2][64 * 64];  // dbuf, interleaved
  __shared__ __align__(16) u16 Ps[4][16 * 64];   // per-wave P, xor-swizzled

  const u16* base = kqv + (size_t)b * SEQ * ROWS3;
  int hcol = h * 64;
  const u16* kbase = base + hcol;                // K_OFF = 0
  const u16* vbase = vt + (size_t)bh * 64 * SEQ;

  // Q fragments: wave owns 32 q-rows = 2 MFMA row-tiles, resident
  bf16x8 qf[2][2];
#pragma unroll
  for (int t = 0; t < 2; ++t) {
    int s = qtile * 128 + wave * 32 + t * 16 + l16;
    const u16* qrow = base + (size_t)s * ROWS3 + 1024 + hcol;  // Q_OFF=1024
    qf[t][0] = *(const bf16x8*)(qrow + quad * 8);
    qf[t][1] = *(const bf16x8*)(qrow + 32 + quad * 8);
  }

  bf16x8 ones;
#pragma unroll
  for (int i = 0; i < 8; ++i) ones[i] = (short)0x3F80;

  f32x4 o[2][4] = {};
  f32x4 ol[2] = {};
  u16* pw = &Ps[wave][0];

  // staging lane mapping: lane l -> row l&7, 16B-chunk l>>3 of an 8-row group
  int prow = lane & 7;
  int pchk = (lane >> 3) * 8;  // elems

  // fragment-read addressing into the interleaved layout
  int rb2 = (l16 >> 3) * 512;  // 8-row sub-block offset (elems)
  int r8 = (l16 & 7) * 8;      // row-within-block offset (elems)

  // swizzled Ps addresses
  int pm8 = (l16 & 7) * 8;
  int prd0 = l16 * 64 + ((quad * 8) ^ pm8);         // pa0 read
  int prd1 = l16 * 64 + ((32 + quad * 8) ^ pm8);    // pa1 read
  int pwr[4];
#pragma unroll
  for (int r = 0; r < 4; ++r) {
    int rho = quad * 4 + r;
    pwr[r] = rho * 64 + ((4 * l16) ^ ((rho & 7) * 8));
  }

  // prologue: stage tile 0 into buffer 0
  {
    const u16* kg = kbase + (size_t)(wave * 16 + prow) * ROWS3 + pchk;
    ASYNC16(kg, &Ks[0][wave * 16 * 64]);
    ASYNC16(kg + (size_t)8 * ROWS3, &Ks[0][(wave * 16 + 8) * 64]);
    const u16* vg = vbase + (size_t)(wave * 16 + prow) * SEQ + pchk;
    ASYNC16(vg, &Vts[0][wave * 16 * 64]);
    ASYNC16(vg + (size_t)8 * SEQ, &Vts[0][(wave * 16 + 8) * 64]);
  }

  int cur = 0;

  for (int t0 = 0; t0 < SEQ; t0 += 64) {
    // b1: own prefetch (now [cur]) drained (vmcnt0); all waves done reading
    // [cur^1] from the previous iteration (lgkm drained on arrival).
    __syncthreads();

    // prefetch next tile into the OTHER buffers; in flight during compute
    if (t0 + 64 < SEQ) {
      const u16* kg = kbase + (size_t)(t0 + 64 + wave * 16 + prow) * ROWS3 + pchk;
      ASYNC16(kg, &Ks[cur ^ 1][wave * 16 * 64]);
      ASYNC16(kg + (size_t)8 * ROWS3, &Ks[cur ^ 1][(wave * 16 + 8) * 64]);
      const u16* vg = vbase + (size_t)(wave * 16 + prow) * SEQ + (t0 + 64) + pchk;
      ASYNC16(vg, &Vts[cur ^ 1][wave * 16 * 64]);
      ASYNC16(vg + (size_t)8 * SEQ, &Vts[cur ^ 1][(wave * 16 + 8) * 64]);
    }

    const u16* ks = &Ks[cur][0];
    const u16* vs = &Vts[cur][0];

    // K fragments: key 16j+l16, d-chunks quad*8 / 32+quad*8 (interleaved addr)
    bf16x8 kf[4][2];
#pragma unroll
    for (int j = 0; j < 4; ++j) {
      kf[j][0] = *(const bf16x8*)&ks[j * 1024 + rb2 + quad * 64 + r8];
      kf[j][1] = *(const bf16x8*)&ks[j * 1024 + rb2 + 256 + quad * 64 + r8];
    }

#pragma unroll
    for (int t = 0; t < 2; ++t) {
      // QK^T for this q-tile (Q pre-scaled by 0.125*log2e)
      f32x4 s[4] = {};
#pragma unroll
      for (int j = 0; j < 4; ++j) {
        s[j] = MFMA(qf[t][0], kf[j][0], s[j]);
        s[j] = MFMA(qf[t][1], kf[j][1], s[j]);
      }
      // exp2 + pack: score s[j][r] = key 16j+l16 -> perm position 4*l16+j
#pragma unroll
      for (int r = 0; r < 4; ++r) {
        float p0 = EXP2(s[0][r]);
        float p1 = EXP2(s[1][r]);
        float p2 = EXP2(s[2][r]);
        float p3 = EXP2(s[3][r]);
        uint2 pk;
        pk.x = pack_bf2(p0, p1);
        pk.y = pack_bf2(p2, p3);
        *(uint2*)&pw[pwr[r]] = pk;
      }
      // P round-trip (wave-synchronous, swizzled) + PV + row-sum
      bf16x8 pa0 = *(const bf16x8*)&pw[prd0];
      bf16x8 pa1 = *(const bf16x8*)&pw[prd1];
#pragma unroll
      for (int d = 0; d < 4; ++d) {
        bf16x8 v0 = *(const bf16x8*)&vs[d * 1024 + rb2 + quad * 64 + r8];
        bf16x8 v1 = *(const bf16x8*)&vs[d * 1024 + rb2 + 256 + quad * 64 + r8];
        o[t][d] = MFMA(pa0, v0, o[t][d]);
        o[t][d] = MFMA(pa1, v1, o[t][d]);
      }
      ol[t] = MFMA(pa0, ones, ol[t]);
      ol[t] = MFMA(pa1, ones, ol[t]);
    }
    cur ^= 1;
  }

  // epilogue: O /= l, merge heads
#pragma unroll
  for (int t = 0; t < 2; ++t)
#pragma unroll
    for (int r = 0; r < 4; ++r) {
      float inv = 1.0f / ol[t][r];
      int s = qtile * 128 + wave * 32 + t * 16 + quad * 4 + r;
      u16* orow = out + (size_t)(b * SEQ + s) * 1024 + hcol;
#pragma unroll
      for (int d = 0; d < 4; ++d) orow[16 * d + l16] = f2bf(o[t][d][r] * inv);
    }
}

extern "C" void kernel_launch(void* const* d_in, const int* in_sizes, int n_in,
                              void* d_out, int out_size, void* d_ws, size_t ws_size,
                              hipStream_t stream) {
  const float* x     = (const float*)d_in[0];
  const float* w_in  = (const float*)d_in[1];
  const float* b_in  = (const float*)d_in[2];
  const float* w_out = (const float*)d_in[3];
  const float* b_out = (const float*)d_in[4];
  float* outp = (float*)d_out;

  char* p = (char*)d_ws;
  u16* wT_in  = (u16*)p; p += (size_t)3072 * 1024 * 2;
  u16* wT_out = (u16*)p; p += (size_t)1024 * 1024 * 2;
  u16* xb     = (u16*)p; p += (size_t)8192 * 1024 * 2;  // reused as vt after GEMM1
  u16* kqv    = (u16*)p; p += (size_t)8192 * 3072 * 2;
  u16* attn   = (u16*)p;
  u16* vtbuf  = xb;  // xb dead after GEMM1; vt is 64*64*2048 u16 = 16 MB

  transpose_to_bf16<<<dim3(3072 / 32, 1024 / 32), dim3(32, 8), 0, stream>>>(w_in, wT_in, 1024, 3072);
  transpose_to_bf16<<<dim3(1024 / 32, 1024 / 32), dim3(32, 8), 0, stream>>>(w_out, wT_out, 1024, 1024);
  f32_to_bf16_vec<<<dim3(8192), dim3(256), 0, stream>>>((const float4*)x, (uint2*)xb);

  const float QSCALE = 0.125f * 1.44269504088896f;
  gemm_bt<0><<<dim3(3072 / BN, 8192 / BM), 256, 0, stream>>>(
      xb, wT_in, b_in, (void*)kqv, 8192, 3072, 1024, 3072, 1024, 2048, QSCALE);

  v_transpose<<<dim3(SEQ / 64, 64), 256, 0, stream>>>(kqv, vtbuf);

  attn_kernel<<<dim3(1024), 256, 0, stream>>>(kqv, vtbuf, attn);

  gemm_bt<1><<<dim3(1024 / BN, 8192 / BM), 256, 0, stream>>>(
      attn, wT_out, b_out, (void*)outp, 8192, 1024, 1024, 1024, 0, 0, 1.0f);
}